// Round 11
// baseline (676.920 us; speedup 1.0000x reference)
//
#include <hip/hip_runtime.h>
#include <hip/hip_bf16.h>

#define BATCH 4
#define CIN 256
#define H 96
#define W 96
#define CC 64
#define OC 32

typedef __attribute__((ext_vector_type(8))) short bf16x8;
typedef __attribute__((ext_vector_type(4))) float f32x4;
typedef __attribute__((ext_vector_type(4))) unsigned short u16x4;
typedef __attribute__((ext_vector_type(4))) unsigned int u32x4;

// workspace layout (bytes)
#define XT_OFF    0
#define WT_OFF    19668992
#define RWT_OFF   19963904
#define FT_OFF    20066304
#define FLAGS_OFF 25186304     // FT_OFF + 5,120,000 (16B-aligned)
// flags (ints): [0]=ticket [1]=wt_cnt [2]=rwt_cnt [3]=border_cnt
//               [4..7]=xt_cnt[b] [8..11]=conv_cnt[b]

__device__ inline unsigned short f2bf(float v) {
    __hip_bfloat16 t = __float2bfloat16(v);
    return *reinterpret_cast<unsigned short*>(&t);
}
__device__ inline float bf2f(short b) {
    return __uint_as_float(((unsigned int)(unsigned short)b) << 16);
}

__device__ inline void gload_lds16(const __hip_bfloat16* g, void* l) {
    __builtin_amdgcn_global_load_lds(
        (const __attribute__((address_space(1))) unsigned int*)g,
        (__attribute__((address_space(3))) unsigned int*)l, 16, 0, 0);
}

// producer: all threads' stores -> per-thread device fence -> barrier -> one
// RELEASE add (device scope; per-XCD L2 non-coherence handled per G16).
__device__ inline void signal_cnt(int* p) {
    __threadfence();
    __syncthreads();
    if (threadIdx.x == 0)
        __hip_atomic_fetch_add(p, 1, __ATOMIC_RELEASE, __HIP_MEMORY_SCOPE_AGENT);
}
// consumer: lane-0 poll (s_sleep backoff) -> barrier -> per-thread acquire fence
__device__ inline void wait_cnt(const int* p, int tgt) {
    if (threadIdx.x == 0) {
        while (__hip_atomic_load(p, __ATOMIC_RELAXED, __HIP_MEMORY_SCOPE_AGENT) < tgt)
            __builtin_amdgcn_s_sleep(8);
    }
    __syncthreads();
    __threadfence();
}

// ===========================================================================
// Job bodies (proven in R8/R10; byte-identical inner loops)
// ===========================================================================

__device__ inline void job_wt(int pb, int tid, const float* __restrict__ ew,
                              __hip_bfloat16* __restrict__ wt)
{
    int idx = pb * 256 + tid;                  // pb in [0,576)
    int e   = idx & 7;
    int m   = (idx >> 3) & 15;
    int cb  = (idx >> 7) & 31;
    int ccg = (idx >> 12) & 3;
    int k   = idx >> 14;
    int cc = ccg * 16 + m, ci = cb * 8 + e;
    wt[idx] = __float2bfloat16(ew[(cc * CIN + ci) * 9 + k]);
}

__device__ inline void job_rwt(int pj, int tid, const float* __restrict__ rw,
                               __hip_bfloat16* __restrict__ rwt)
{
    int idx = pj * 256 + tid;                  // pj in [0,200): 51200 exact
    int e    = idx & 7;
    int lane = (idx >> 3) & 63;
    int mt   = (idx >> 9) & 1;
    int kc   = idx >> 10;
    int g = lane >> 4, m = lane & 15;
    int o  = mt * 16 + m;
    int k  = kc * 32 + g * 8 + e;
    int uv = k >> 6, c = k & 63;
    rwt[idx] = __float2bfloat16(rw[(o * CC + c) * 25 + uv]);
}

__device__ inline void job_border(int pj, int tid, __hip_bfloat16* __restrict__ ft)
{
    int idx = pj * 256 + tid;                  // pj in [0,98): 25088 exact
    int b = idx / 6272, t = idx % 6272;
    int q = t & 7, pid = t >> 3;
    int r, c;
    if (pid < 400) {
        int rr = pid / 100;
        r = (rr < 2) ? rr : rr + 96;
        c = pid % 100;
    } else {
        int p2 = pid - 400;
        r = 2 + (p2 >> 2);
        int c2 = p2 & 3;
        c = (c2 < 2) ? c2 : c2 + 96;
    }
    *(u32x4*)(ft + ((size_t)((b * 100 + r) * 100 + c)) * 64 + q * 8) = (u32x4){0u,0u,0u,0u};
}

__device__ inline void job_xtrow(int b, int r, int tid,
    __hip_bfloat16 (*lds)[264], const float* __restrict__ x,
    __hip_bfloat16* __restrict__ xt)
{
    __hip_bfloat16* rowp = xt + ((size_t)(b * 98 + r)) * 98 * 256;
    const int gi = r - 1;

    if (gi < 0 || gi >= H) {
        u32x4* p = (u32x4*)rowp;
        const u32x4 z = (u32x4){0u,0u,0u,0u};
        for (int t = tid; t < 98 * 256 * 2 / 16; t += 256) p[t] = z;
        return;
    }
    const int xorv = tid & 7;
    for (int cich = 0; cich < 8; ++cich) {
        int ci = cich * 32 + (tid >> 3);
        int ci_sw = (((ci >> 3) ^ xorv) << 3) | (ci & 7);
        const float* src = x + ((size_t)((b * CIN + ci) * H + gi)) * W;
        for (int coli = 0; coli < 3; ++coli) {
            int col = coli * 32 + (tid & 7) * 4;
            float4 v = *(const float4*)(src + col);
            lds[col + 0][ci_sw] = __float2bfloat16(v.x);
            lds[col + 1][ci_sw] = __float2bfloat16(v.y);
            lds[col + 2][ci_sw] = __float2bfloat16(v.z);
            lds[col + 3][ci_sw] = __float2bfloat16(v.w);
        }
    }
    __syncthreads();
    u32x4* dst16 = (u32x4*)rowp;
#pragma unroll
    for (int it = 0; it < 12; ++it) {
        int u = it * 256 + tid;
        int col = u >> 5, ci8 = u & 31;
        int unit_sw = ci8 ^ ((col >> 2) & 7);
        u32x4 v = *(const u32x4*)&lds[col][unit_sw * 8];
        dst16[(col + 1) * 32 + ci8] = v;
    }
    if (tid < 32) dst16[tid] = (u32x4){0u,0u,0u,0u};
    else if (tid < 64) dst16[97 * 32 + (tid - 32)] = (u32x4){0u,0u,0u,0u};
}

__device__ inline void job_conv(int job, int tid, char* bbuf,
    const __hip_bfloat16* __restrict__ xt, const __hip_bfloat16* __restrict__ wt,
    const float* __restrict__ eb, __hip_bfloat16* __restrict__ ft)
{
    const int jb = job % 3;
    const int iq = (job / 3) % 24;
    const int zz = job / 72;                   // b*2 + ch (b-major)
    const int b = zz >> 1, ch = zz & 1;
    const int j0 = jb * 32, i0 = iq * 4;
    const int wid = tid >> 6;
    const int lane = tid & 63;
    const int g = lane >> 4, m = lane & 15;

    const int start = (wid < 2) ? wid * 256 : 512 + (wid - 2) * 192;
    const int nslot = (wid < 2) ? 4 : 3;

    const __hip_bfloat16* src0; const __hip_bfloat16* src1;
    const __hip_bfloat16* src2; const __hip_bfloat16* src3;
    int dst0, dst1, dst2, dst3;
#define SLOT_INIT(J, SRC, DST)                                                  \
    {                                                                           \
        int U = start + (J) * 64 + lane;                                        \
        if (U > 863) U = 863;                                                   \
        int s = U & 3, pxr = U >> 2;                                            \
        int px = pxr % 36, r = pxr / 36;                                        \
        int q = s ^ ((px >> 1) & 3);                                            \
        SRC = xt + ((size_t)((b * 98 + i0 + r) * 98 + j0 + px)) * 256 + q * 8;  \
        DST = (start + (J) * 64) * 16;                                          \
    }
    SLOT_INIT(0, src0, dst0)
    SLOT_INIT(1, src1, dst1)
    SLOT_INIT(2, src2, dst2)
    SLOT_INIT(3, src3, dst3)
#undef SLOT_INIT

#define STAGE(T, NB)                                                            \
    {                                                                           \
        const int co = (T) * 32;                                                \
        char* lb = bbuf + (NB) * 14336;                                         \
        gload_lds16(src0 + co, lb + dst0);                                      \
        gload_lds16(src1 + co, lb + dst1);                                      \
        gload_lds16(src2 + co, lb + dst2);                                      \
        if (nslot > 3) gload_lds16(src3 + co, lb + dst3);                       \
    }

    STAGE(0, 0)
    __syncthreads();

    f32x4 acc00 = (f32x4){0.f,0.f,0.f,0.f}, acc01 = (f32x4){0.f,0.f,0.f,0.f};
    f32x4 acc10 = (f32x4){0.f,0.f,0.f,0.f}, acc11 = (f32x4){0.f,0.f,0.f,0.f};

    const __hip_bfloat16* wA = wt + (ch * 2) * 4096 + g * 128 + m * 8;

    for (int t = 0; t < 8; ++t) {
        if (t < 7) STAGE(t + 1, (t + 1) & 1)

        const char* bb = bbuf + (t & 1) * 14336;
        const __hip_bfloat16* wa = wA + t * 512;
#pragma unroll
        for (int ku = 0; ku < 3; ++ku) {
#pragma unroll
            for (int kv = 0; kv < 3; ++kv) {
                const int k = ku * 3 + kv;
                bf16x8 a0 = *(const bf16x8*)(wa + k * 16384);
                bf16x8 a1 = *(const bf16x8*)(wa + k * 16384 + 4096);
                const int r = wid + ku;
                const int px0 = m + kv, px1 = px0 + 16;
                bf16x8 b0 = *(const bf16x8*)(bb + ((r * 36 + px0) * 4 + (g ^ ((px0 >> 1) & 3))) * 16);
                bf16x8 b1 = *(const bf16x8*)(bb + ((r * 36 + px1) * 4 + (g ^ ((px1 >> 1) & 3))) * 16);
                acc00 = __builtin_amdgcn_mfma_f32_16x16x32_bf16(a0, b0, acc00, 0, 0, 0);
                acc01 = __builtin_amdgcn_mfma_f32_16x16x32_bf16(a0, b1, acc01, 0, 0, 0);
                acc10 = __builtin_amdgcn_mfma_f32_16x16x32_bf16(a1, b0, acc10, 0, 0, 0);
                acc11 = __builtin_amdgcn_mfma_f32_16x16x32_bf16(a1, b1, acc11, 0, 0, 0);
            }
        }
        __syncthreads();
    }
#undef STAGE

    __hip_bfloat16* out = ft + ((size_t)((b * 100 + i0 + wid + 2) * 100 + (j0 + 2))) * 64;
#pragma unroll
    for (int mt = 0; mt < 2; ++mt) {
        const int ccb = (ch * 2 + mt) * 16 + g * 4;
        float bias[4];
#pragma unroll
        for (int r = 0; r < 4; ++r) bias[r] = eb[ccb + r];
        f32x4 aN0 = (mt == 0) ? acc00 : acc10;
        f32x4 aN1 = (mt == 0) ? acc01 : acc11;
        u16x4 p0, p1;
#pragma unroll
        for (int r = 0; r < 4; ++r) {
            p0[r] = f2bf(aN0[r] + bias[r]);
            p1[r] = f2bf(aN1[r] + bias[r]);
        }
        *(u16x4*)(out + (0 * 16 + m) * 64 + ccb) = p0;
        *(u16x4*)(out + (1 * 16 + m) * 64 + ccb) = p1;
    }
}

__device__ inline void job_corrproj(int job, int tid, char* wnd, char* asub,
    const __hip_bfloat16* __restrict__ ft, const __hip_bfloat16* __restrict__ rwt,
    const float* __restrict__ rb, float* __restrict__ y)
{
    const int jb = job % 3;
    const int iy = (job / 3) % 48;
    const int b  = job / 144;
    const int jc0 = jb * 32, i0 = iy * 2;
    const int wave = tid >> 6, lane = tid & 63;
    const int g = lane >> 4, m = lane & 15;
    const int rw2 = wave >> 1, pw = wave & 1;

    {
        const __hip_bfloat16* ftb = ft + ((size_t)((b * 100 + i0) * 100 + jc0)) * 64;
        const int base = wave * 448;
        const int nw = (wave == 3) ? 6 : 7;
        for (int j = 0; j < nw; ++j) {
            int U = base + j * 64 + lane;
            int q = U & 7, rc = U >> 3;
            int col = rc % 36, r = rc / 36;
            gload_lds16(ftb + (size_t)(r * 100 + col) * 64 + (q ^ (col & 7)) * 8,
                        wnd + (base + j * 64) * 16);
        }
    }
    const int abase = (wave < 2) ? wave * 192 : 384 + (wave - 2) * 128;
    const int anw = (wave < 2) ? 3 : 2;
#define STAGE_A(SC, NB)                                                         \
    {                                                                           \
        const __hip_bfloat16* s = rwt + (SC) * 5120;                            \
        for (int j = 0; j < anw; ++j) {                                         \
            int U = abase + j * 64;                                             \
            gload_lds16(s + (size_t)(U + lane) * 8, asub + (NB) * 10240 + U * 16); \
        }                                                                       \
    }
    STAGE_A(0, 0)
    __syncthreads();

    float cen[16];
    {
        const int colc = pw * 16 + m + 2;
        const char* cb = wnd + ((rw2 + 2) * 36 + colc) * 128;
        bf16x8 c0 = *(const bf16x8*)(cb + ((g ^ (colc & 7)) << 4));
        bf16x8 c1 = *(const bf16x8*)(cb + (((4 + g) ^ (colc & 7)) << 4));
#pragma unroll
        for (int e = 0; e < 8; ++e) {
            cen[e]     = bf2f(c0[e]);
            cen[8 + e] = bf2f(c1[e]);
        }
    }

    f32x4 acc0 = (f32x4){0.f, 0.f, 0.f, 0.f};
    f32x4 acc1 = (f32x4){0.f, 0.f, 0.f, 0.f};

    for (int sc = 0; sc < 10; ++sc) {
        if (sc < 9) STAGE_A(sc + 1, (sc + 1) & 1)

        const char* ab = asub + (sc & 1) * 10240;
#pragma unroll
        for (int kk = 0; kk < 5; ++kk) {
            const int kc = sc * 5 + kk;
            const int uv = kc >> 1, h = kc & 1;
            const int u = uv / 5, v = uv - u * 5;
            bf16x8 a0 = *(const bf16x8*)(ab + (kk * 2 + 0) * 1024 + lane * 16);
            bf16x8 a1 = *(const bf16x8*)(ab + (kk * 2 + 1) * 1024 + lane * 16);
            const int col = pw * 16 + m + v;
            const char* sb = wnd + ((rw2 + u) * 36 + col) * 128;
            bf16x8 s = *(const bf16x8*)(sb + (((h * 4 + g) ^ (col & 7)) << 4));
            bf16x8 hb;
#pragma unroll
            for (int e = 0; e < 8; ++e)
                hb[e] = (short)f2bf(bf2f(s[e]) * cen[h * 8 + e]);
            acc0 = __builtin_amdgcn_mfma_f32_16x16x32_bf16(a0, hb, acc0, 0, 0, 0);
            acc1 = __builtin_amdgcn_mfma_f32_16x16x32_bf16(a1, hb, acc1, 0, 0, 0);
        }
        __syncthreads();
    }
#undef STAGE_A

    const int i = i0 + rw2, j0 = jc0 + pw * 16;
#pragma unroll
    for (int r = 0; r < 4; ++r) {
        int o0 = g * 4 + r;
        y[((size_t)(b * OC + o0) * H + i) * W + j0 + m] = acc0[r] + rb[o0];
        int o1 = 16 + g * 4 + r;
        y[((size_t)(b * OC + o1) * H + i) * W + j0 + m] = acc1[r] + rb[o1];
    }
}

// ===========================================================================
// Ticket-fused kernel: 2418 tickets, flags in d_ws (zeroed by memset).
// Ticket map: [0,576) wt | [576,776) rwt | [776,874) ft-border |
//             [874,1266) xt rows (b-major) | [1266,1842) conv |
//             [1842,2418) corrproj.
// Deadlock-free: every wait targets strictly lower tickets; lowest unfinished
// grabbed ticket always has satisfied deps; ungrabbed tickets get slots as
// blocks retire.
// ===========================================================================
union SharedU {
    __hip_bfloat16 prep[96][264];          // 50,688 B
    char conv[2 * 14336];                  // 28,672 B
    struct { char wnd[1728 * 16]; char asub[2 * 10240]; } cp; // 48,128 B
};

__global__ __launch_bounds__(256) void fused_ticket_kernel(
    const float* __restrict__ x, const float* __restrict__ ew,
    const float* __restrict__ eb, const float* __restrict__ rw,
    const float* __restrict__ rb, float* __restrict__ y,
    __hip_bfloat16* __restrict__ xt, __hip_bfloat16* __restrict__ wt,
    __hip_bfloat16* __restrict__ rwt, __hip_bfloat16* __restrict__ ft,
    int* __restrict__ flags)
{
    __shared__ SharedU sh;
    __shared__ int sjob;
    const int tid = threadIdx.x;

    if (tid == 0)
        sjob = __hip_atomic_fetch_add(&flags[0], 1, __ATOMIC_RELAXED,
                                      __HIP_MEMORY_SCOPE_AGENT);
    __syncthreads();
    const int job = sjob;

    if (job < 576) {
        job_wt(job, tid, ew, wt);
        signal_cnt(&flags[1]);
    } else if (job < 776) {
        job_rwt(job - 576, tid, rw, rwt);
        signal_cnt(&flags[2]);
    } else if (job < 874) {
        job_border(job - 776, tid, ft);
        signal_cnt(&flags[3]);
    } else if (job < 1266) {
        const int rj = job - 874;
        const int b = rj / 98, r = rj % 98;
        job_xtrow(b, r, tid, sh.prep, x, xt);
        signal_cnt(&flags[4 + b]);
    } else if (job < 1842) {
        const int cj = job - 1266;
        const int b = cj / 144;
        wait_cnt(&flags[1], 576);        // wt packed
        wait_cnt(&flags[4 + b], 98);     // xt batch b complete
        job_conv(cj, tid, sh.conv, xt, wt, eb, ft);
        signal_cnt(&flags[8 + b]);
    } else {
        const int pj = job - 1842;
        const int b = pj / 144;
        wait_cnt(&flags[2], 200);        // rwt packed
        wait_cnt(&flags[3], 98);         // ft border zeroed
        wait_cnt(&flags[8 + b], 144);    // conv batch b complete
        job_corrproj(pj, tid, sh.cp.wnd, sh.cp.asub, ft, rwt, rb, y);
    }
}

// ===========================================================================
// Fallback standalone kernels (proven R7/R8 path; used only if ws too small)
// ===========================================================================
__global__ __launch_bounds__(256) void prep_xt_kernel(
    const float* __restrict__ x, const float* __restrict__ ew,
    const float* __restrict__ rw, __hip_bfloat16* __restrict__ xt,
    __hip_bfloat16* __restrict__ wt, __hip_bfloat16* __restrict__ rwt,
    __hip_bfloat16* __restrict__ ft)
{
    __shared__ __align__(16) __hip_bfloat16 lds[96][264];
    const int bid = blockIdx.x;
    const int tid = threadIdx.x;
    if (bid < 392) {
        job_xtrow(bid / 98, bid % 98, tid, lds, x, xt);
    } else {
        for (int pb = bid - 392; pb < 874; pb += 184) {
            if (pb < 576) job_wt(pb, tid, ew, wt);
            else if (pb < 776) job_rwt(pb - 576, tid, rw, rwt);
            else job_border(pb - 776, tid, ft);
        }
    }
}

__global__ __launch_bounds__(256) void conv_mfma4_kernel(
    const __hip_bfloat16* __restrict__ xt, const __hip_bfloat16* __restrict__ wt,
    const float* __restrict__ eb, __hip_bfloat16* __restrict__ ft)
{
    __shared__ __align__(16) char bbuf[2 * 14336];
    job_conv(blockIdx.x, threadIdx.x, bbuf, xt, wt, eb, ft);
}

__global__ __launch_bounds__(256) void corrproj_mfma3_kernel(
    const __hip_bfloat16* __restrict__ ft, const __hip_bfloat16* __restrict__ rwt,
    const float* __restrict__ rb, float* __restrict__ y)
{
    __shared__ __align__(16) char wnd[1728 * 16];
    __shared__ __align__(16) char asub[2 * 10240];
    job_corrproj(blockIdx.x, threadIdx.x, wnd, asub, ft, rwt, rb, y);
}

extern "C" void kernel_launch(void* const* d_in, const int* in_sizes, int n_in,
                              void* d_out, int out_size, void* d_ws, size_t ws_size,
                              hipStream_t stream) {
    const float* x  = (const float*)d_in[0];
    const float* ew = (const float*)d_in[1];
    const float* eb = (const float*)d_in[2];
    const float* rw = (const float*)d_in[3];
    const float* rb = (const float*)d_in[4];
    float* y = (float*)d_out;

    char* ws = (char*)d_ws;
    __hip_bfloat16* xt  = (__hip_bfloat16*)(ws + XT_OFF);
    __hip_bfloat16* wt  = (__hip_bfloat16*)(ws + WT_OFF);
    __hip_bfloat16* rwt = (__hip_bfloat16*)(ws + RWT_OFF);
    __hip_bfloat16* ft  = (__hip_bfloat16*)(ws + FT_OFF);
    int* flags = (int*)(ws + FLAGS_OFF);

    if (ws_size >= FLAGS_OFF + 64) {
        hipMemsetAsync(flags, 0, 64, stream);
        fused_ticket_kernel<<<2418, 256, 0, stream>>>(
            x, ew, eb, rw, rb, y, xt, wt, rwt, ft, flags);
    } else {
        prep_xt_kernel<<<576, 256, 0, stream>>>(x, ew, rw, xt, wt, rwt, ft);
        conv_mfma4_kernel<<<576, 256, 0, stream>>>(xt, wt, eb, ft);
        corrproj_mfma3_kernel<<<576, 256, 0, stream>>>(ft, rwt, rb, y);
    }
}

// Round 12
// 54.215 us; speedup vs baseline: 12.4857x; 12.4857x over previous
//
#include <hip/hip_runtime.h>
#include <hip/hip_bf16.h>

#define BATCH 4
#define CIN 256
#define H 96
#define W 96
#define CC 64
#define OC 32

typedef __attribute__((ext_vector_type(8))) short bf16x8;
typedef __attribute__((ext_vector_type(4))) float f32x4;
typedef __attribute__((ext_vector_type(4))) unsigned short u16x4;
typedef __attribute__((ext_vector_type(4))) unsigned int u32x4;

// workspace layout (bytes)
//   xt : [4][98][98][256] bf16 = 19,668,992
//   wt : [9][4][32][16][8] bf16 =    294,912
//   rwt: [50][2][64][8]   bf16 =    102,400
//   ft : [4][100][100][64] bf16 =  5,120,000
#define XT_OFF  0
#define WT_OFF  19668992
#define RWT_OFF 19963904
#define FT_OFF  20066304

__device__ inline unsigned short f2bf(float v) {
    __hip_bfloat16 t = __float2bfloat16(v);
    return *reinterpret_cast<unsigned short*>(&t);
}
__device__ inline float bf2f(short b) {
    return __uint_as_float(((unsigned int)(unsigned short)b) << 16);
}

// async global->LDS, 16B per lane; LDS dest is wave-uniform base (+lane*16 HW)
__device__ inline void gload_lds16(const __hip_bfloat16* g, void* l) {
    __builtin_amdgcn_global_load_lds(
        (const __attribute__((address_space(1))) unsigned int*)g,
        (__attribute__((address_space(3))) unsigned int*)l, 16, 0, 0);
}

// ---------------------------------------------------------------------------
// Merged prologue+transpose kernel (exact 54.18-µs R7 configuration).
// bid <  392 : xt rows — x -> bf16 channel-last zero-padded xt[b][98][98][256]
// bid >= 392 : pb = bid-392: [0,576) wt pack, [576,776) rwt pack,
//              [776,874) ft border zero.  Grid 1266.
// ---------------------------------------------------------------------------
__global__ __launch_bounds__(256) void prep_xt_kernel(
    const float* __restrict__ x, const float* __restrict__ ew,
    const float* __restrict__ rw, __hip_bfloat16* __restrict__ xt,
    __hip_bfloat16* __restrict__ wt, __hip_bfloat16* __restrict__ rwt,
    __hip_bfloat16* __restrict__ ft)
{
    const int bid = blockIdx.x;
    const int tid = threadIdx.x;

    if (bid >= 392) {
        const int pb = bid - 392;
        if (pb < 576) {
            // wt[k][ccg][cb][m][e] = ew[ccg*16+m][cb*8+e][k]
            int idx = pb * 256 + tid;
            int e   = idx & 7;
            int m   = (idx >> 3) & 15;
            int cb  = (idx >> 7) & 31;
            int ccg = (idx >> 12) & 3;
            int k   = idx >> 14;
            int cc = ccg * 16 + m, ci = cb * 8 + e;
            wt[idx] = __float2bfloat16(ew[(cc * CIN + ci) * 9 + k]);
        } else if (pb < 776) {
            // rwt[((kc*2+mt)*64 + lane)*8 + e]; k = kc*32+g*8+e; uv=k>>6; c=k&63
            int idx = (pb - 576) * 256 + tid;
            if (idx >= 50 * 2 * 64 * 8) return;
            int e    = idx & 7;
            int lane = (idx >> 3) & 63;
            int mt   = (idx >> 9) & 1;
            int kc   = idx >> 10;
            int g = lane >> 4, m = lane & 15;
            int o  = mt * 16 + m;
            int k  = kc * 32 + g * 8 + e;
            int uv = k >> 6, c = k & 63;
            rwt[idx] = __float2bfloat16(rw[(o * CC + c) * 25 + uv]);
        } else {
            // zero ft border (interior overwritten by conv)
            int idx = (pb - 776) * 256 + tid;
            if (idx >= 4 * 6272) return;
            int b = idx / 6272, t = idx % 6272;
            int q = t & 7, pid = t >> 3;
            int r, c;
            if (pid < 400) {
                int rr = pid / 100;
                r = (rr < 2) ? rr : rr + 96;
                c = pid % 100;
            } else {
                int p2 = pid - 400;
                r = 2 + (p2 >> 2);
                int c2 = p2 & 3;
                c = (c2 < 2) ? c2 : c2 + 96;
            }
            *(u32x4*)(ft + ((size_t)((b * 100 + r) * 100 + c)) * 64 + q * 8) = (u32x4){0u,0u,0u,0u};
        }
        return;
    }

    // ---- xt transpose part ----
    const int r = bid % 98;            // padded row
    const int b = bid / 98;
    __hip_bfloat16* rowp = xt + ((size_t)(b * 98 + r)) * 98 * 256;
    const int gi = r - 1;

    if (gi < 0 || gi >= H) {           // border row: zero-fill (16B stores)
        u32x4* p = (u32x4*)rowp;
        const u32x4 z = (u32x4){0u,0u,0u,0u};
        for (int t = tid; t < 98 * 256 * 2 / 16; t += 256) p[t] = z;
        return;
    }

    __shared__ __align__(16) __hip_bfloat16 lds[96][264];   // 528 B rows

    // phase 1: coalesced fp32 reads, scalar cvt into transposed LDS
    for (int cich = 0; cich < 8; ++cich) {
        int ci = cich * 32 + (tid >> 3);
        const float* src = x + ((size_t)((b * CIN + ci) * H + gi)) * W;
        for (int coli = 0; coli < 3; ++coli) {
            int col = coli * 32 + (tid & 7) * 4;
            float4 v = *(const float4*)(src + col);
            lds[col + 0][ci] = __float2bfloat16(v.x);
            lds[col + 1][ci] = __float2bfloat16(v.y);
            lds[col + 2][ci] = __float2bfloat16(v.z);
            lds[col + 3][ci] = __float2bfloat16(v.w);
        }
    }
    __syncthreads();

    // phase 2: b128 LDS reads, 16B coalesced global stores
    u32x4* dst16 = (u32x4*)rowp;
#pragma unroll
    for (int it = 0; it < 12; ++it) {
        int u = it * 256 + tid;        // 0..3071
        int col = u >> 5, ci8 = u & 31;
        u32x4 v = *(const u32x4*)&lds[col][ci8 * 8];
        dst16[(col + 1) * 32 + ci8] = v;
    }
    if (tid < 32) dst16[tid] = (u32x4){0u,0u,0u,0u};
    else if (tid < 64) dst16[97 * 32 + (tid - 32)] = (u32x4){0u,0u,0u,0u};
}

// ---------------------------------------------------------------------------
// Conv v4 + XCD swizzle: 1D grid 576, job = (bid&7)*72 + (bid>>3) so XCD k
// owns zz = k (one batch-ch slice: xt working set 4.9 MB -> L2-resident,
// halo re-reads become same-XCD L2 hits). Inner code identical to 54.18 run:
// 4 waves = 4 output rows, same cc-half; B via global_load_lds with
// both-sides XOR involution; 2-phase double-buffer.
// ---------------------------------------------------------------------------
__global__ __launch_bounds__(256) void conv_mfma4_kernel(
    const __hip_bfloat16* __restrict__ xt, const __hip_bfloat16* __restrict__ wt,
    const float* __restrict__ eb, __hip_bfloat16* __restrict__ ft)
{
    const int bid = blockIdx.x;
    const int job = (bid & 7) * 72 + (bid >> 3);   // bijective: 576 = 8*72
    const int jb = job % 3;
    const int iq = (job / 3) % 24;
    const int zz = job / 72;           // b*2 + ch
    const int b = zz >> 1, ch = zz & 1;
    const int j0 = jb * 32, i0 = iq * 4;
    const int tid = threadIdx.x;
    const int wid = tid >> 6;          // 0..3 = output-row offset
    const int lane = tid & 63;
    const int g = lane >> 4, m = lane & 15;

    __shared__ __align__(16) char bbuf[2][14336];   // 896 units x 16B per buf

    const int start = (wid < 2) ? wid * 256 : 512 + (wid - 2) * 192;
    const int nslot = (wid < 2) ? 4 : 3;

    const __hip_bfloat16* src0; const __hip_bfloat16* src1;
    const __hip_bfloat16* src2; const __hip_bfloat16* src3;
    int dst0, dst1, dst2, dst3;
#define SLOT_INIT(J, SRC, DST)                                                  \
    {                                                                           \
        int U = start + (J) * 64 + lane;                                        \
        if (U > 863) U = 863;                                                   \
        int s = U & 3, pxr = U >> 2;                                            \
        int px = pxr % 36, r = pxr / 36;                                        \
        int q = s ^ ((px >> 1) & 3);                                            \
        SRC = xt + ((size_t)((b * 98 + i0 + r) * 98 + j0 + px)) * 256 + q * 8;  \
        DST = (start + (J) * 64) * 16;                                          \
    }
    SLOT_INIT(0, src0, dst0)
    SLOT_INIT(1, src1, dst1)
    SLOT_INIT(2, src2, dst2)
    SLOT_INIT(3, src3, dst3)
#undef SLOT_INIT

#define STAGE(T, NB)                                                            \
    {                                                                           \
        const int co = (T) * 32;                                                \
        char* lb = &bbuf[(NB)][0];                                              \
        gload_lds16(src0 + co, lb + dst0);                                      \
        gload_lds16(src1 + co, lb + dst1);                                      \
        gload_lds16(src2 + co, lb + dst2);                                      \
        if (nslot > 3) gload_lds16(src3 + co, lb + dst3);                       \
    }

    // prologue: stage chunk 0
    STAGE(0, 0)
    __syncthreads();

    f32x4 acc00 = (f32x4){0.f,0.f,0.f,0.f}, acc01 = (f32x4){0.f,0.f,0.f,0.f};
    f32x4 acc10 = (f32x4){0.f,0.f,0.f,0.f}, acc11 = (f32x4){0.f,0.f,0.f,0.f};

    // A: ccg = ch*2 + mt; identical addresses for all 4 waves of the block
    const __hip_bfloat16* wA = wt + (ch * 2) * 4096 + g * 128 + m * 8;

    for (int t = 0; t < 8; ++t) {
        if (t < 7) STAGE(t + 1, (t + 1) & 1)

        const char* bb = &bbuf[t & 1][0];
        const __hip_bfloat16* wa = wA + t * 512;
#pragma unroll
        for (int ku = 0; ku < 3; ++ku) {
#pragma unroll
            for (int kv = 0; kv < 3; ++kv) {
                const int k = ku * 3 + kv;
                bf16x8 a0 = *(const bf16x8*)(wa + k * 16384);
                bf16x8 a1 = *(const bf16x8*)(wa + k * 16384 + 4096);
                const int r = wid + ku;
                const int px0 = m + kv, px1 = px0 + 16;
                bf16x8 b0 = *(const bf16x8*)(bb + ((r * 36 + px0) * 4 + (g ^ ((px0 >> 1) & 3))) * 16);
                bf16x8 b1 = *(const bf16x8*)(bb + ((r * 36 + px1) * 4 + (g ^ ((px1 >> 1) & 3))) * 16);
                acc00 = __builtin_amdgcn_mfma_f32_16x16x32_bf16(a0, b0, acc00, 0, 0, 0);
                acc01 = __builtin_amdgcn_mfma_f32_16x16x32_bf16(a0, b1, acc01, 0, 0, 0);
                acc10 = __builtin_amdgcn_mfma_f32_16x16x32_bf16(a1, b0, acc10, 0, 0, 0);
                acc11 = __builtin_amdgcn_mfma_f32_16x16x32_bf16(a1, b1, acc11, 0, 0, 0);
            }
        }
        __syncthreads();
    }
#undef STAGE

    // epilogue -> ft[b][i0+wid+2][j0+2+px][cc]
    __hip_bfloat16* out = ft + ((size_t)((b * 100 + i0 + wid + 2) * 100 + (j0 + 2))) * 64;
#pragma unroll
    for (int mt = 0; mt < 2; ++mt) {
        const int ccb = (ch * 2 + mt) * 16 + g * 4;
        float bias[4];
#pragma unroll
        for (int r = 0; r < 4; ++r) bias[r] = eb[ccb + r];
        f32x4 aN0 = (mt == 0) ? acc00 : acc10;
        f32x4 aN1 = (mt == 0) ? acc01 : acc11;
        u16x4 p0, p1;
#pragma unroll
        for (int r = 0; r < 4; ++r) {
            p0[r] = f2bf(aN0[r] + bias[r]);
            p1[r] = f2bf(aN1[r] + bias[r]);
        }
        *(u16x4*)(out + (0 * 16 + m) * 64 + ccb) = p0;
        *(u16x4*)(out + (1 * 16 + m) * 64 + ccb) = p1;
    }
}

// ---------------------------------------------------------------------------
// CorrProj v2 (the 54.18-µs version: reg-staged wnd + reg-prefetched asub)
// + XCD swizzle: 1D grid 576, job = (bid&7)*72 + (bid>>3) -> XCD k owns a
// contiguous half-batch of ft (2.5 MB, L2-resident).
// ---------------------------------------------------------------------------
__global__ __launch_bounds__(256) void corrproj_mfma2_kernel(
    const __hip_bfloat16* __restrict__ ft, const __hip_bfloat16* __restrict__ rwt,
    const float* __restrict__ rb, float* __restrict__ y)
{
    const int bid = blockIdx.x;
    const int job = (bid & 7) * 72 + (bid >> 3);   // bijective: 576 = 8*72
    const int jb = job % 3;
    const int iy = (job / 3) % 48;
    const int b  = job / 144;
    const int jc0 = jb * 32, i0 = iy * 2;
    const int tid = threadIdx.x;
    const int wave = tid >> 6, lane = tid & 63;
    const int g = lane >> 4, m = lane & 15;
    const int rw = wave >> 1, pw = wave & 1;

    __shared__ __align__(16) char wnd[6 * 36 * 128];      // 27648 B
    __shared__ __align__(16) char asub[2][5 * 2 * 1024];  // 2 x 10240 B

    // ---- stage ft window: rows i0..i0+5, cols jc0..jc0+35, 64 ci, swizzled
    {
        const __hip_bfloat16* base = ft + ((size_t)((b * 100 + i0) * 100 + jc0)) * 64;
#pragma unroll
        for (int it = 0; it < 7; ++it) {
            int u = it * 256 + tid;
            if (u < 1728) {
                int q = u & 7, rc = u >> 3;
                int col = rc % 36, r = rc / 36;
                u32x4 v = *(const u32x4*)(base + ((size_t)(r * 100 + col)) * 64 + q * 8);
                *(u32x4*)(wnd + (r * 36 + col) * 128 + ((q ^ (col & 7)) << 4)) = v;
            }
        }
    }
    // ---- stage A super-chunk 0 (kc 0..4)
    {
        const u32x4* src = (const u32x4*)rwt;
        u32x4* dst = (u32x4*)&asub[0][0];
        dst[tid] = src[tid];
        dst[tid + 256] = src[tid + 256];
        if (tid < 128) dst[tid + 512] = src[tid + 512];
    }
    __syncthreads();

    // center cache (f32): window[rw+2][pw*16+m+2][h*32+g*8 ..]
    float cen[16];
    {
        const int colc = pw * 16 + m + 2;
        const char* cb = wnd + ((rw + 2) * 36 + colc) * 128;
        bf16x8 c0 = *(const bf16x8*)(cb + ((g ^ (colc & 7)) << 4));
        bf16x8 c1 = *(const bf16x8*)(cb + (((4 + g) ^ (colc & 7)) << 4));
#pragma unroll
        for (int e = 0; e < 8; ++e) {
            cen[e]     = bf2f(c0[e]);
            cen[8 + e] = bf2f(c1[e]);
        }
    }

    f32x4 acc0 = (f32x4){0.f, 0.f, 0.f, 0.f};
    f32x4 acc1 = (f32x4){0.f, 0.f, 0.f, 0.f};

    for (int sc = 0; sc < 10; ++sc) {
        // prefetch next A super-chunk into regs (latency hides under compute)
        u32x4 p0, p1, p2;
        const bool pf = (sc < 9);
        if (pf) {
            const u32x4* src = (const u32x4*)rwt + (sc + 1) * 640;
            p0 = src[tid];
            p1 = src[tid + 256];
            if (tid < 128) p2 = src[tid + 512];
        }

        const char* ab = &asub[sc & 1][0];
#pragma unroll
        for (int kk = 0; kk < 5; ++kk) {
            const int kc = sc * 5 + kk;
            const int uv = kc >> 1, h = kc & 1;
            const int u = uv / 5, v = uv - u * 5;
            bf16x8 a0 = *(const bf16x8*)(ab + (kk * 2 + 0) * 1024 + lane * 16);
            bf16x8 a1 = *(const bf16x8*)(ab + (kk * 2 + 1) * 1024 + lane * 16);
            const int col = pw * 16 + m + v;
            const char* sb = wnd + ((rw + u) * 36 + col) * 128;
            bf16x8 s = *(const bf16x8*)(sb + (((h * 4 + g) ^ (col & 7)) << 4));
            bf16x8 hb;
#pragma unroll
            for (int e = 0; e < 8; ++e)
                hb[e] = (short)f2bf(bf2f(s[e]) * cen[h * 8 + e]);
            acc0 = __builtin_amdgcn_mfma_f32_16x16x32_bf16(a0, hb, acc0, 0, 0, 0);
            acc1 = __builtin_amdgcn_mfma_f32_16x16x32_bf16(a1, hb, acc1, 0, 0, 0);
        }

        if (pf) {
            u32x4* dst = (u32x4*)&asub[(sc + 1) & 1][0];
            dst[tid] = p0;
            dst[tid + 256] = p1;
            if (tid < 128) dst[tid + 512] = p2;
        }
        __syncthreads();
    }

    // epilogue: D[o][px]: o = mt*16 + g*4 + r, px col = m
    const int i = i0 + rw, j0 = jc0 + pw * 16;
#pragma unroll
    for (int r = 0; r < 4; ++r) {
        int o0 = g * 4 + r;
        y[((size_t)(b * OC + o0) * H + i) * W + j0 + m] = acc0[r] + rb[o0];
        int o1 = 16 + g * 4 + r;
        y[((size_t)(b * OC + o1) * H + i) * W + j0 + m] = acc1[r] + rb[o1];
    }
}

extern "C" void kernel_launch(void* const* d_in, const int* in_sizes, int n_in,
                              void* d_out, int out_size, void* d_ws, size_t ws_size,
                              hipStream_t stream) {
    const float* x  = (const float*)d_in[0];
    const float* ew = (const float*)d_in[1];
    const float* eb = (const float*)d_in[2];
    const float* rw = (const float*)d_in[3];
    const float* rb = (const float*)d_in[4];
    float* y = (float*)d_out;

    char* ws = (char*)d_ws;
    __hip_bfloat16* xt  = (__hip_bfloat16*)(ws + XT_OFF);
    __hip_bfloat16* wt  = (__hip_bfloat16*)(ws + WT_OFF);
    __hip_bfloat16* rwt = (__hip_bfloat16*)(ws + RWT_OFF);
    __hip_bfloat16* ft  = (__hip_bfloat16*)(ws + FT_OFF);

    prep_xt_kernel<<<1266, 256, 0, stream>>>(x, ew, rw, xt, wt, rwt, ft);
    conv_mfma4_kernel<<<576, 256, 0, stream>>>(xt, wt, eb, ft);
    corrproj_mfma2_kernel<<<576, 256, 0, stream>>>(ft, rwt, rb, y);
}